// Round 1
// baseline (3380.316 us; speedup 1.0000x reference)
//
#include <hip/hip_runtime.h>
#include <hip/hip_bf16.h>
#include <string.h>

#define ALPHA 0.01f
#define BETA  0.125f
#define NN    2048
#define NOBS  512
#define NB    16
#define TT    512

typedef __attribute__((ext_vector_type(8))) short short8;
typedef __attribute__((ext_vector_type(4))) float f32x4;

// Persistent device-side scratch (no ws_size assumptions).
__device__ __align__(16) unsigned short g_wbf[NN * NN];        // W as bf16 bits, [i][k]
__device__ __align__(16) float          g_xf[2][NB * NN];      // fp32 state (clamped input x_eff)
__device__ __align__(16) unsigned short g_xbf[2][NB * NN];     // bf16 copy of state for MFMA

__device__ inline unsigned short f2bf(float f) {
    unsigned int x = __builtin_bit_cast(unsigned int, f);
    // round-to-nearest-even to bf16
    unsigned int r = (x + 0x7fffu + ((x >> 16) & 1u)) >> 16;
    return (unsigned short)r;
}

__global__ void convert_w_kernel(const float* __restrict__ w) {
    int n4 = NN * NN / 4;
    const float4* w4 = reinterpret_cast<const float4*>(w);
    for (int i = blockIdx.x * blockDim.x + threadIdx.x; i < n4;
         i += gridDim.x * blockDim.x) {
        float4 v = w4[i];
        ushort4 o;
        o.x = f2bf(v.x); o.y = f2bf(v.y); o.z = f2bf(v.z); o.w = f2bf(v.w);
        reinterpret_cast<ushort4*>(g_wbf)[i] = o;
    }
}

// Build x0, write output column 0, init state buffers (slot 0).
__global__ void init_kernel(const float* __restrict__ xt, float* __restrict__ out) {
    int idx = blockIdx.x * blockDim.x + threadIdx.x;  // 16*2048 total
    if (idx >= NB * NN) return;
    int b = idx >> 11;       // / 2048
    int i = idx & (NN - 1);
    float v = (i < NOBS) ? xt[(size_t)b * NOBS * TT + (size_t)i * TT + 0] : 0.0f;
    out[(size_t)b * NN * TT + (size_t)i * TT + 0] = v;
    g_xf[0][idx]  = v;
    g_xbf[0][idx] = f2bf(v);
}

// One recurrence step:  s = 0.99*x_eff + 0.01*(x_eff @ W^T)
// grid = 128 blocks (16 neurons each) x 256 threads (4 waves, K split 4x512).
__global__ __launch_bounds__(256)
void step_kernel(const float* __restrict__ teach, float* __restrict__ out,
                 int p, int out_col, int clamp_col) {
    int tid = threadIdx.x;
    int wv  = tid >> 6;       // wave 0..3 -> K slice
    int l   = tid & 63;       // lane
    int ln  = l & 15;         // A-row (batch) / B-col (neuron) lane index
    int kg  = l >> 4;         // k-group 0..3
    int i0  = blockIdx.x << 4;  // neuron tile base

    const unsigned short* xbf = g_xbf[p];
    const float*          xf  = g_xf[p];

    // Same (lane,elem)->k mapping for A and B: k = wv*512 + it*32 + kg*8 + j
    const short8* A = reinterpret_cast<const short8*>(xbf + (size_t)ln * NN + wv * 512 + kg * 8);
    const short8* B = reinterpret_cast<const short8*>(g_wbf + (size_t)(i0 + ln) * NN + wv * 512 + kg * 8);

    f32x4 acc = {0.f, 0.f, 0.f, 0.f};
#pragma unroll
    for (int it = 0; it < 16; ++it) {
        short8 a = A[it * 4];   // +it*32 elements
        short8 b = B[it * 4];
        acc = __builtin_amdgcn_mfma_f32_16x16x32_bf16(a, b, acc, 0, 0, 0);
    }

    // D layout (verified): col = lane&15 (neuron), row = (lane>>4)*4 + r (batch)
    __shared__ float red[4][16][16];
#pragma unroll
    for (int r = 0; r < 4; ++r) red[wv][kg * 4 + r][ln] = acc[r];
    __syncthreads();

    int b = tid >> 4;   // batch
    int n = tid & 15;   // neuron local
    float sum = red[0][b][n] + red[1][b][n] + red[2][b][n] + red[3][b][n];
    int ig = i0 + n;
    size_t sidx = (size_t)b * NN + ig;
    float s = (1.0f - ALPHA) * xf[sidx] + ALPHA * sum;

    if (out_col >= 0)
        out[(size_t)b * NN * TT + (size_t)ig * TT + out_col] = s;

    float nx = s;
    if (clamp_col >= 0 && ig < NOBS)
        nx = BETA * teach[(size_t)b * NOBS * TT + (size_t)ig * TT + clamp_col] + (1.0f - BETA) * s;

    g_xf[p ^ 1][sidx]  = nx;
    g_xbf[p ^ 1][sidx] = f2bf(nx);
}

extern "C" void kernel_launch(void* const* d_in, const int* in_sizes, int n_in,
                              void* d_out, int out_size, void* d_ws, size_t ws_size,
                              hipStream_t stream) {
    const float* xt = (const float*)d_in[0];   // (16, 512, 512)
    const float* w  = (const float*)d_in[1];   // (2048, 2048)
    float* out = (float*)d_out;                // (16, 2048, 512)

    hipLaunchKernelGGL(convert_w_kernel, dim3(1024), dim3(256), 0, stream, w);
    hipLaunchKernelGGL(init_kernel, dim3(128), dim3(256), 0, stream, xt, out);

    // 512 sequential fmodel applications.
    // s=0: produces x1 (no output), clamps with teacher col 1.
    // s=1..511: produce output col s; clamp with col s+1 (except s=511).
    for (int s = 0; s < TT; ++s) {
        int p = s & 1;
        int out_col   = (s == 0) ? -1 : s;
        int clamp_col = (s < TT - 1) ? (s + 1) : -1;
        hipLaunchKernelGGL(step_kernel, dim3(128), dim3(256), 0, stream,
                           xt, out, p, out_col, clamp_col);
    }
}